// Round 1
// baseline (203.320 us; speedup 1.0000x reference)
//
#include <hip/hip_runtime.h>

#define N_TOKENS 131072
#define D_MODEL  512
#define PATHS    16
#define CAP      16384            // CAP_FACTOR * N / P = 2*131072/16
#define TPB      256
#define NBLK     (N_TOKENS / TPB) // 512
#define F4_ROW   (D_MODEL / 4)    // 128 float4 per token row

// ---------------------------------------------------------------------------
// Kernel 1: per-token argmax (first-max wins) + ordered rank within block +
// per-block per-path histogram.
// ---------------------------------------------------------------------------
__global__ void k_argmax_hist(const float* __restrict__ score,
                              int* __restrict__ packed,
                              int* __restrict__ blkcnt) {
    __shared__ int wcount[TPB / 64][PATHS];
    const int t    = blockIdx.x * TPB + threadIdx.x;
    const int lane = threadIdx.x & 63;
    const int wid  = threadIdx.x >> 6;

    const float4* s4 = reinterpret_cast<const float4*>(score) + (size_t)t * 4;
    float4 a = s4[0], b = s4[1], c = s4[2], d = s4[3];
    float v[16] = {a.x, a.y, a.z, a.w, b.x, b.y, b.z, b.w,
                   c.x, c.y, c.z, c.w, d.x, d.y, d.z, d.w};
    int   myp  = 0;
    float best = v[0];
#pragma unroll
    for (int p = 1; p < 16; ++p) {
        if (v[p] > best) { best = v[p]; myp = p; }   // strict > == first occurrence
    }

    unsigned long long mymask = 0ULL;
#pragma unroll
    for (int p = 0; p < PATHS; ++p) {
        unsigned long long m = __ballot(myp == p);
        if (p == myp) mymask = m;
        if (lane == p) wcount[wid][p] = __popcll(m); // lane p records path p's count
    }
    const int rank_w = __popcll(mymask & ((1ULL << lane) - 1ULL));
    __syncthreads();

    int prefix = 0;
    for (int w = 0; w < wid; ++w) prefix += wcount[w][myp];
    packed[t] = (myp << 16) | (prefix + rank_w);

    if (threadIdx.x < PATHS) {
        int s = 0;
#pragma unroll
        for (int w = 0; w < TPB / 64; ++w) s += wcount[w][threadIdx.x];
        blkcnt[blockIdx.x * PATHS + threadIdx.x] = s;
    }
}

// ---------------------------------------------------------------------------
// Kernel 2: exclusive scan of per-block counts (per path), single block.
// Dep chain is just 512 integer adds per path; loads pipeline through LDS.
// ---------------------------------------------------------------------------
__global__ void k_scan(int* __restrict__ blkcnt, int* __restrict__ cnt) {
    __shared__ int s[NBLK * PATHS];  // 32 KiB
    for (int i = threadIdx.x; i < NBLK * PATHS; i += blockDim.x) s[i] = blkcnt[i];
    __syncthreads();
    if (threadIdx.x < PATHS) {
        const int p = threadIdx.x;
        int run = 0;
        for (int b = 0; b < NBLK; ++b) {
            int c = s[b * PATHS + p];
            s[b * PATHS + p] = run;
            run += c;
        }
        cnt[p] = run;
    }
    __syncthreads();
    for (int i = threadIdx.x; i < NBLK * PATHS; i += blockDim.x) blkcnt[i] = s[i];
}

// ---------------------------------------------------------------------------
// Kernel 3: final position = block offset + rank; scatter token id into slot.
// Tokens past capacity are dropped (never happens statistically, but correct).
// ---------------------------------------------------------------------------
__global__ void k_slots(const int* __restrict__ packed,
                        const int* __restrict__ blkoff,
                        int* __restrict__ slot_token) {
    const int t  = blockIdx.x * TPB + threadIdx.x;
    const int pk = packed[t];
    const int p  = pk >> 16;
    const int r  = pk & 0xffff;
    const int pos = blkoff[blockIdx.x * PATHS + p] + r;
    if (pos < CAP) slot_token[p * CAP + pos] = t;
}

// ---------------------------------------------------------------------------
// Kernel 4: fully-coalesced streaming producer of the output. One float4 per
// thread-iteration; filled slots gather the contiguous 2 KB input row.
// ---------------------------------------------------------------------------
__global__ void k_gather(const float* __restrict__ inputs,
                         const int* __restrict__ slot_token,
                         const int* __restrict__ cnt,
                         float4* __restrict__ out) {
    const size_t total  = (size_t)PATHS * CAP * F4_ROW;  // 33,554,432 float4
    const size_t stride = (size_t)gridDim.x * blockDim.x;
    for (size_t i = (size_t)blockIdx.x * blockDim.x + threadIdx.x; i < total;
         i += stride) {
        const size_t row = i >> 7;             // /128 float4 per row
        const int    c   = (int)(i & 127);
        const int    p   = (int)(row >> 14);   // CAP = 2^14
        const int    j   = (int)(row & (CAP - 1));
        float4 v = make_float4(0.f, 0.f, 0.f, 0.f);
        if (j < cnt[p]) {
            const int tok = slot_token[row];
            v = reinterpret_cast<const float4*>(inputs)[(size_t)tok * F4_ROW + c];
        }
        out[i] = v;
    }
}

// ---------------------------------------------------------------------------
extern "C" void kernel_launch(void* const* d_in, const int* in_sizes, int n_in,
                              void* d_out, int out_size, void* d_ws, size_t ws_size,
                              hipStream_t stream) {
    const float* inputs = (const float*)d_in[0];
    const float* score  = (const float*)d_in[1];
    float*       out    = (float*)d_out;

    // Workspace layout (ints): packed[N] | blkcnt[NBLK*P] | cnt[P] | slot_token[P*CAP]
    int* w          = (int*)d_ws;
    int* packed     = w;
    int* blkcnt     = packed + N_TOKENS;
    int* cnt        = blkcnt + NBLK * PATHS;
    int* slot_token = cnt + PATHS;

    k_argmax_hist<<<NBLK, TPB, 0, stream>>>(score, packed, blkcnt);
    k_scan<<<1, TPB, 0, stream>>>(blkcnt, cnt);
    k_slots<<<NBLK, TPB, 0, stream>>>(packed, blkcnt, slot_token);
    k_gather<<<8192, TPB, 0, stream>>>(inputs, slot_token, cnt, (float4*)out);
}

// Round 2
// 192.756 us; speedup vs baseline: 1.0548x; 1.0548x over previous
//
#include <hip/hip_runtime.h>

#define N_TOKENS 131072
#define D_MODEL  512
#define PATHS    16
#define CAP      16384            // CAP_FACTOR * N / P = 2*131072/16
#define TPB      256
#define NBLK     (N_TOKENS / TPB) // 512 argmax blocks
#define F4_ROW   (D_MODEL / 4)    // 128 float4 per token row
#define TOK_PER_BLK 16            // tokens per scatter block

// ---------------------------------------------------------------------------
// Kernel 1: per-token argmax (first-max wins) + ordered rank within block +
// per-block per-path histogram.
// ---------------------------------------------------------------------------
__global__ void k_argmax_hist(const float* __restrict__ score,
                              int* __restrict__ packed,
                              int* __restrict__ blkcnt) {
    __shared__ int wcount[TPB / 64][PATHS];
    const int t    = blockIdx.x * TPB + threadIdx.x;
    const int lane = threadIdx.x & 63;
    const int wid  = threadIdx.x >> 6;

    const float4* s4 = reinterpret_cast<const float4*>(score) + (size_t)t * 4;
    float4 a = s4[0], b = s4[1], c = s4[2], d = s4[3];
    float v[16] = {a.x, a.y, a.z, a.w, b.x, b.y, b.z, b.w,
                   c.x, c.y, c.z, c.w, d.x, d.y, d.z, d.w};
    int   myp  = 0;
    float best = v[0];
#pragma unroll
    for (int p = 1; p < 16; ++p) {
        if (v[p] > best) { best = v[p]; myp = p; }   // strict > == first occurrence
    }

    unsigned long long mymask = 0ULL;
#pragma unroll
    for (int p = 0; p < PATHS; ++p) {
        unsigned long long m = __ballot(myp == p);
        if (p == myp) mymask = m;
        if (lane == p) wcount[wid][p] = __popcll(m); // lane p records path p's count
    }
    const int rank_w = __popcll(mymask & ((1ULL << lane) - 1ULL));
    __syncthreads();

    int prefix = 0;
    for (int w = 0; w < wid; ++w) prefix += wcount[w][myp];
    packed[t] = (myp << 16) | (prefix + rank_w);

    if (threadIdx.x < PATHS) {
        int s = 0;
#pragma unroll
        for (int w = 0; w < TPB / 64; ++w) s += wcount[w][threadIdx.x];
        blkcnt[blockIdx.x * PATHS + threadIdx.x] = s;
    }
}

// ---------------------------------------------------------------------------
// Kernel 2: exclusive scan of per-block counts (per path), single block.
// ---------------------------------------------------------------------------
__global__ void k_scan(int* __restrict__ blkcnt, int* __restrict__ cnt) {
    __shared__ int s[NBLK * PATHS];  // 32 KiB
    for (int i = threadIdx.x; i < NBLK * PATHS; i += blockDim.x) s[i] = blkcnt[i];
    __syncthreads();
    if (threadIdx.x < PATHS) {
        const int p = threadIdx.x;
        int run = 0;
        for (int b = 0; b < NBLK; ++b) {
            int c = s[b * PATHS + p];
            s[b * PATHS + p] = run;
            run += c;
        }
        cnt[p] = run;
    }
    __syncthreads();
    for (int i = threadIdx.x; i < NBLK * PATHS; i += blockDim.x) blkcnt[i] = s[i];
}

// ---------------------------------------------------------------------------
// Kernel 3: token-ordered scatter. Sequential input reads (32 KB contiguous
// per block), random 2 KB row writes. 16 tokens per block; destination rows
// staged in LDS by the first 16 threads.
// ---------------------------------------------------------------------------
__global__ void k_scatter(const float4* __restrict__ inputs,
                          const int* __restrict__ packed,
                          const int* __restrict__ blkoff,
                          float4* __restrict__ out) {
    __shared__ int dst_row[TOK_PER_BLK];
    const int base = blockIdx.x * TOK_PER_BLK;

    if (threadIdx.x < TOK_PER_BLK) {
        const int t  = base + threadIdx.x;
        const int pk = packed[t];
        const int p  = pk >> 16;
        const int r  = pk & 0xffff;
        const int pos = blkoff[(t >> 8) * PATHS + p] + r;
        dst_row[threadIdx.x] = (pos < CAP) ? (p * CAP + pos) : -1;  // -1 = dropped
    }
    __syncthreads();

    const int col = threadIdx.x & (F4_ROW - 1);       // 0..127
    const int sub = threadIdx.x >> 7;                 // 0..1 (2 tokens per pass)
#pragma unroll
    for (int it = 0; it < TOK_PER_BLK / 2; ++it) {
        const int rl  = it * 2 + sub;
        const int dst = dst_row[rl];
        const float4 v = inputs[(size_t)(base + rl) * F4_ROW + col];
        if (dst >= 0) out[(size_t)dst * F4_ROW + col] = v;
    }
}

// ---------------------------------------------------------------------------
// Kernel 4: zero the contiguous empty tail of each path: rows cnt[p]..CAP-1.
// Pure sequential writes (predicated per-row, whole waves skip filled rows).
// ---------------------------------------------------------------------------
__global__ void k_zero_tail(const int* __restrict__ cnt,
                            float4* __restrict__ out) {
    __shared__ int c[PATHS];
    if (threadIdx.x < PATHS) c[threadIdx.x] = cnt[threadIdx.x];
    __syncthreads();

    const int total_rows = PATHS * CAP;               // 262144
    const int rows_per_pass = (gridDim.x * blockDim.x) >> 7;  // threads/128
    const int col = threadIdx.x & (F4_ROW - 1);
    int row = ((blockIdx.x * blockDim.x + threadIdx.x) >> 7);
    const float4 z = make_float4(0.f, 0.f, 0.f, 0.f);
    for (; row < total_rows; row += rows_per_pass) {
        const int p = row >> 14;                      // CAP = 2^14
        const int j = row & (CAP - 1);
        if (j >= c[p]) out[(size_t)row * F4_ROW + col] = z;
    }
}

// ---------------------------------------------------------------------------
extern "C" void kernel_launch(void* const* d_in, const int* in_sizes, int n_in,
                              void* d_out, int out_size, void* d_ws, size_t ws_size,
                              hipStream_t stream) {
    const float* inputs = (const float*)d_in[0];
    const float* score  = (const float*)d_in[1];
    float*       out    = (float*)d_out;

    // Workspace (ints): packed[N] | blkcnt[NBLK*P] | cnt[P]
    int* w      = (int*)d_ws;
    int* packed = w;
    int* blkcnt = packed + N_TOKENS;
    int* cnt    = blkcnt + NBLK * PATHS;

    k_argmax_hist<<<NBLK, TPB, 0, stream>>>(score, packed, blkcnt);
    k_scan<<<1, TPB, 0, stream>>>(blkcnt, cnt);
    k_zero_tail<<<2048, TPB, 0, stream>>>(cnt, (float4*)out);
    k_scatter<<<N_TOKENS / TOK_PER_BLK, TPB, 0, stream>>>(
        (const float4*)inputs, packed, blkcnt, (float4*)out);
}

// Round 3
// 191.336 us; speedup vs baseline: 1.0626x; 1.0074x over previous
//
#include <hip/hip_runtime.h>

#define N_TOKENS 131072
#define D_MODEL  512
#define PATHS    16
#define CAP      16384            // CAP_FACTOR * N / P
#define TPB      256
#define NBLK     (N_TOKENS / TPB) // 512 token blocks
#define F4_ROW   (D_MODEL / 4)    // 128 float4 per row

#define SC_WGS      (NBLK * PATHS)        // 8192 scatter workgroups
#define ZERO_WGS    2048
#define TOTAL_WGS   (SC_WGS + ZERO_WGS)   // 10240 (every 5th wg zeroes)
#define ROWS_TOTAL  (PATHS * CAP)         // 262144
#define ROWS_PER_ZWG (ROWS_TOTAL / ZERO_WGS) // 128 contiguous rows / zero-wg

// ---------------------------------------------------------------------------
// Kernel 1: per-token argmax (first-max wins) + stable rank within block +
// per-block per-path histogram.
// ---------------------------------------------------------------------------
__global__ void k_argmax_hist(const float* __restrict__ score,
                              int* __restrict__ packed,
                              int* __restrict__ blkcnt) {
    __shared__ int wcount[TPB / 64][PATHS];
    const int t    = blockIdx.x * TPB + threadIdx.x;
    const int lane = threadIdx.x & 63;
    const int wid  = threadIdx.x >> 6;

    const float4* s4 = reinterpret_cast<const float4*>(score) + (size_t)t * 4;
    float4 a = s4[0], b = s4[1], c = s4[2], d = s4[3];
    float v[16] = {a.x, a.y, a.z, a.w, b.x, b.y, b.z, b.w,
                   c.x, c.y, c.z, c.w, d.x, d.y, d.z, d.w};
    int   myp  = 0;
    float best = v[0];
#pragma unroll
    for (int p = 1; p < 16; ++p) {
        if (v[p] > best) { best = v[p]; myp = p; }   // strict > == first occurrence
    }

    unsigned long long mymask = 0ULL;
#pragma unroll
    for (int p = 0; p < PATHS; ++p) {
        unsigned long long m = __ballot(myp == p);
        if (p == myp) mymask = m;
        if (lane == p) wcount[wid][p] = __popcll(m);
    }
    const int rank_w = __popcll(mymask & ((1ULL << lane) - 1ULL));
    __syncthreads();

    int prefix = 0;
    for (int w = 0; w < wid; ++w) prefix += wcount[w][myp];
    packed[t] = (myp << 16) | (prefix + rank_w);

    if (threadIdx.x < PATHS) {
        int s = 0;
#pragma unroll
        for (int w = 0; w < TPB / 64; ++w) s += wcount[w][threadIdx.x];
        blkcnt[blockIdx.x * PATHS + threadIdx.x] = s;
    }
}

// ---------------------------------------------------------------------------
// Kernel 2: exclusive scan of per-block counts (per path), single block.
// ---------------------------------------------------------------------------
__global__ void k_scan(int* __restrict__ blkcnt, int* __restrict__ cnt) {
    __shared__ int s[NBLK * PATHS];  // 32 KiB
    for (int i = threadIdx.x; i < NBLK * PATHS; i += blockDim.x) s[i] = blkcnt[i];
    __syncthreads();
    if (threadIdx.x < PATHS) {
        const int p = threadIdx.x;
        int run = 0;
        for (int b = 0; b < NBLK; ++b) {
            int c = s[b * PATHS + p];
            s[b * PATHS + p] = run;
            run += c;
        }
        cnt[p] = run;
    }
    __syncthreads();
    for (int i = threadIdx.x; i < NBLK * PATHS; i += blockDim.x) blkcnt[i] = s[i];
}

// ---------------------------------------------------------------------------
// Kernel 3 (fused): destination-ordered scatter + contiguous zero-tail.
//   bid with (bid+1)%5==0  -> zero-wg over 128 contiguous output rows
//   otherwise              -> scatter-wg (p, blk): contiguous output segment
// ---------------------------------------------------------------------------
__global__ void k_dispatch(const float4* __restrict__ inputs,
                           const int* __restrict__ packed,
                           const int* __restrict__ blkoff,
                           const int* __restrict__ cnt,
                           float4* __restrict__ out) {
    const int bid = blockIdx.x;
    const int col = threadIdx.x & (F4_ROW - 1);   // 0..127
    const int sub = threadIdx.x >> 7;             // 0..1 (2 rows per pass)

    if ((bid + 1) % 5 == 0) {
        // ---- zero workgroup: rows [zid*128, zid*128+128), single path ----
        const int zid  = bid / 5;
        const int row0 = zid * ROWS_PER_ZWG;
        const int p    = row0 >> 14;              // 128 | 16384, path constant
        const int cp   = cnt[p];
        const float4 z = make_float4(0.f, 0.f, 0.f, 0.f);
        for (int r = sub; r < ROWS_PER_ZWG; r += 2) {
            const int row = row0 + r;
            if ((row & (CAP - 1)) >= cp) out[(size_t)row * F4_ROW + col] = z;
        }
        return;
    }

    // ---- scatter workgroup ----
    const int sid = bid - (bid + 1) / 5;          // 0..8191
    const int p   = sid / NBLK;                   // path (write-contiguous order)
    const int blk = sid % NBLK;                   // token block

    __shared__ int lds_tok[TPB];
    __shared__ int lds_k;
    if (threadIdx.x == 0) lds_k = 0;
    __syncthreads();

    const int pk    = packed[blk * TPB + threadIdx.x];
    const bool match = (pk >> 16) == p;
    if (match) lds_tok[pk & 0xffff] = threadIdx.x;
    unsigned long long m = __ballot(match);
    if ((threadIdx.x & 63) == 0) atomicAdd(&lds_k, __popcll(m));
    __syncthreads();

    const int k    = lds_k;
    const int base = blkoff[blk * PATHS + p];
    const size_t in_row0  = (size_t)blk * TPB;
    const size_t out_row0 = (size_t)p * CAP + base;

    // 1-deep software pipeline: keep the next row-load in flight.
    int i = sub;
    if (i < k) {
        float4 v = inputs[(in_row0 + lds_tok[i]) * F4_ROW + col];
        for (int nx = i + 2; nx < k; nx += 2) {
            float4 v2 = inputs[(in_row0 + lds_tok[nx]) * F4_ROW + col];
            if (base + i < CAP) out[(out_row0 + i) * F4_ROW + col] = v;
            v = v2; i = nx;
        }
        if (base + i < CAP) out[(out_row0 + i) * F4_ROW + col] = v;
    }
}

// ---------------------------------------------------------------------------
extern "C" void kernel_launch(void* const* d_in, const int* in_sizes, int n_in,
                              void* d_out, int out_size, void* d_ws, size_t ws_size,
                              hipStream_t stream) {
    const float* inputs = (const float*)d_in[0];
    const float* score  = (const float*)d_in[1];
    float*       out    = (float*)d_out;

    // Workspace (ints): packed[N] | blkcnt[NBLK*P] | cnt[P]
    int* w      = (int*)d_ws;
    int* packed = w;
    int* blkcnt = packed + N_TOKENS;
    int* cnt    = blkcnt + NBLK * PATHS;

    k_argmax_hist<<<NBLK, TPB, 0, stream>>>(score, packed, blkcnt);
    k_scan<<<1, TPB, 0, stream>>>(blkcnt, cnt);
    k_dispatch<<<TOTAL_WGS, TPB, 0, stream>>>(
        (const float4*)inputs, packed, blkcnt, cnt, (float4*)out);
}

// Round 5
// 177.347 us; speedup vs baseline: 1.1465x; 1.0789x over previous
//
#include <hip/hip_runtime.h>

typedef float f32x4 __attribute__((ext_vector_type(4)));

#define N_TOKENS 131072
#define D_MODEL  512
#define PATHS    16
#define CAP      16384            // CAP_FACTOR * N / P
#define TPB      256
#define NBLK     (N_TOKENS / TPB) // 512 token blocks
#define F4_ROW   (D_MODEL / 4)    // 128 f32x4 per row
#define ROWS_TOTAL (PATHS * CAP)  // 262144
#define R_PER_WG 64               // rows per fill workgroup
#define FILL_WGS (ROWS_TOTAL / R_PER_WG) // 4096

// ---------------------------------------------------------------------------
// Kernel 1: per-token argmax (first-max wins) + stable rank within block +
// per-block per-path histogram.
// ---------------------------------------------------------------------------
__global__ void k_argmax_hist(const float* __restrict__ score,
                              int* __restrict__ packed,
                              int* __restrict__ blkcnt) {
    __shared__ int wcount[TPB / 64][PATHS];
    const int t    = blockIdx.x * TPB + threadIdx.x;
    const int lane = threadIdx.x & 63;
    const int wid  = threadIdx.x >> 6;

    const f32x4* s4 = reinterpret_cast<const f32x4*>(score) + (size_t)t * 4;
    f32x4 a = s4[0], b = s4[1], c = s4[2], d = s4[3];
    float v[16] = {a.x, a.y, a.z, a.w, b.x, b.y, b.z, b.w,
                   c.x, c.y, c.z, c.w, d.x, d.y, d.z, d.w};
    int   myp  = 0;
    float best = v[0];
#pragma unroll
    for (int p = 1; p < 16; ++p) {
        if (v[p] > best) { best = v[p]; myp = p; }   // strict > == first occurrence
    }

    unsigned long long mymask = 0ULL;
#pragma unroll
    for (int p = 0; p < PATHS; ++p) {
        unsigned long long m = __ballot(myp == p);
        if (p == myp) mymask = m;
        if (lane == p) wcount[wid][p] = __popcll(m);
    }
    const int rank_w = __popcll(mymask & ((1ULL << lane) - 1ULL));
    __syncthreads();

    int prefix = 0;
    for (int w = 0; w < wid; ++w) prefix += wcount[w][myp];
    packed[t] = (myp << 16) | (prefix + rank_w);

    if (threadIdx.x < PATHS) {
        int s = 0;
#pragma unroll
        for (int w = 0; w < TPB / 64; ++w) s += wcount[w][threadIdx.x];
        blkcnt[blockIdx.x * PATHS + threadIdx.x] = s;
    }
}

// ---------------------------------------------------------------------------
// Kernel 2: parallel two-level exclusive scan of blkcnt (per path).
// 256 threads: thread = (chunk c = tid>>4, path p = tid&15); 32 blocks/chunk.
// ---------------------------------------------------------------------------
__global__ void k_scan(int* __restrict__ blkcnt, int* __restrict__ cnt) {
    __shared__ int part[16][PATHS + 1];
    const int p = threadIdx.x & 15;
    const int c = threadIdx.x >> 4;
    const int base = c * 32;

    int local[32];
#pragma unroll
    for (int b = 0; b < 32; ++b) local[b] = blkcnt[(base + b) * PATHS + p];
    int s = 0;
#pragma unroll
    for (int b = 0; b < 32; ++b) { int v = local[b]; local[b] = s; s += v; }
    part[c][p] = s;
    __syncthreads();

    if (threadIdx.x < PATHS) {
        int run = 0;
#pragma unroll
        for (int ch = 0; ch < 16; ++ch) {
            int v = part[ch][threadIdx.x];
            part[ch][threadIdx.x] = run;
            run += v;
        }
        cnt[threadIdx.x] = run;
    }
    __syncthreads();

    const int off = part[c][p];
#pragma unroll
    for (int b = 0; b < 32; ++b) blkcnt[(base + b) * PATHS + p] = local[b] + off;
}

// ---------------------------------------------------------------------------
// Kernel 3: slot_token[p*CAP + pos] = token id (inverse permutation).
// ---------------------------------------------------------------------------
__global__ void k_slots(const int* __restrict__ packed,
                        const int* __restrict__ blkoff,
                        int* __restrict__ slot_token) {
    const int t  = blockIdx.x * TPB + threadIdx.x;
    const int pk = packed[t];
    const int p  = pk >> 16;
    const int r  = pk & 0xffff;
    const int pos = blkoff[blockIdx.x * PATHS + p] + r;
    if (pos < CAP) slot_token[p * CAP + pos] = t;
}

// ---------------------------------------------------------------------------
// Kernel 4: fill. Each wg owns 64 contiguous output rows of one path.
// Indices staged in LDS up front -> hot loop has no dependent index loads,
// compiler pipelines the row gathers 4-deep. Filled region is a prefix, so
// zero rows are a branch-free contiguous tail. Nontemporal on big streams.
// ---------------------------------------------------------------------------
__global__ void k_fill(const f32x4* __restrict__ inputs,
                       const int* __restrict__ slot_token,
                       const int* __restrict__ cnt,
                       f32x4* __restrict__ out) {
    __shared__ int toks[R_PER_WG];
    const int row0 = blockIdx.x * R_PER_WG;
    const int p    = row0 >> 14;               // CAP = 2^14
    const int cp   = cnt[p];
    if (threadIdx.x < R_PER_WG)
        toks[threadIdx.x] = slot_token[row0 + threadIdx.x];
    __syncthreads();

    const int col = threadIdx.x & (F4_ROW - 1);
    const int sub = threadIdx.x >> 7;          // 0..1
    const int jrel = row0 & (CAP - 1);
    int ndata = cp - jrel;
    ndata = ndata < 0 ? 0 : (ndata > R_PER_WG ? R_PER_WG : ndata);

    // data rows [0, ndata): gather (2 rows per pass across the block)
#pragma unroll 4
    for (int r = sub; r < ndata; r += 2) {
        const f32x4 v = __builtin_nontemporal_load(
            &inputs[(size_t)toks[r] * F4_ROW + col]);
        __builtin_nontemporal_store(v, &out[(size_t)(row0 + r) * F4_ROW + col]);
    }
    // zero rows [ndata, 64): branch-free contiguous tail
    const f32x4 z = {0.f, 0.f, 0.f, 0.f};
#pragma unroll 4
    for (int rz = ndata + ((sub - ndata) & 1); rz < R_PER_WG; rz += 2) {
        __builtin_nontemporal_store(z, &out[(size_t)(row0 + rz) * F4_ROW + col]);
    }
}

// ---------------------------------------------------------------------------
extern "C" void kernel_launch(void* const* d_in, const int* in_sizes, int n_in,
                              void* d_out, int out_size, void* d_ws, size_t ws_size,
                              hipStream_t stream) {
    const float* inputs = (const float*)d_in[0];
    const float* score  = (const float*)d_in[1];
    float*       out    = (float*)d_out;

    // Workspace (ints): packed[N] | blkcnt[NBLK*P] | cnt[P] | slot_token[P*CAP]
    int* w          = (int*)d_ws;
    int* packed     = w;
    int* blkcnt     = packed + N_TOKENS;
    int* cnt        = blkcnt + NBLK * PATHS;
    int* slot_token = cnt + PATHS;

    k_argmax_hist<<<NBLK, TPB, 0, stream>>>(score, packed, blkcnt);
    k_scan<<<1, TPB, 0, stream>>>(blkcnt, cnt);
    k_slots<<<NBLK, TPB, 0, stream>>>(packed, blkcnt, slot_token);
    k_fill<<<FILL_WGS, TPB, 0, stream>>>(
        (const f32x4*)inputs, slot_token, cnt, (f32x4*)out);
}